// Round 1
// baseline (126.865 us; speedup 1.0000x reference)
//
#include <hip/hip_runtime.h>
#include <math.h>

#define HF 37
#define WF 50
#define CC 512
#define POOLD 7
#define SAMPD 14

typedef float nfloat4 __attribute__((ext_vector_type(4)));

__device__ __forceinline__ float4 lerp4(float4 a, float4 b, float t) {
    float4 r;
    r.x = a.x + t * (b.x - a.x);
    r.y = a.y + t * (b.y - a.y);
    r.z = a.z + t * (b.z - a.z);
    r.w = a.w + t * (b.w - a.w);
    return r;
}

__device__ __forceinline__ float4 max4(float4 a, float4 b) {
    float4 r;
    r.x = fmaxf(a.x, b.x);
    r.y = fmaxf(a.y, b.y);
    r.z = fmaxf(a.z, b.z);
    r.w = fmaxf(a.w, b.w);
    return r;
}

__device__ __forceinline__ void store_nt4(float* p, float4 v) {
    nfloat4 nv;
    nv.x = v.x; nv.y = v.y; nv.z = v.z; nv.w = v.w;
    __builtin_nontemporal_store(nv, (nfloat4*)p);
}

// Raw (un-lerped) rows of one feature column. RC: 0 = 2 rows, 1 = 3 rows, 2 = 4 rows.
struct Raw { float4 a, b, c, d; };

template <int RC>
__device__ __forceinline__ Raw loadraw(const float* __restrict__ pbase, int col,
                                       int ro0, int ro1, int ro2, int ro3) {
    const float* p = pbase + (size_t)col * CC;
    Raw r;
    r.a = *(const float4*)(p + ro0);
    r.b = *(const float4*)(p + ro1);
    if (RC == 1) { r.c = *(const float4*)(p + ro3); }
    if (RC == 2) { r.c = *(const float4*)(p + ro2); r.d = *(const float4*)(p + ro3); }
    return r;
}

template <int RC>
__device__ __forceinline__ void vlerp(const Raw& r, float wya, float wyb,
                                      float4& va, float4& vb) {
    if (RC == 0)      { va = lerp4(r.a, r.b, wya); vb = lerp4(r.a, r.b, wyb); }
    else if (RC == 1) { va = lerp4(r.a, r.b, wya); vb = lerp4(r.b, r.c, wyb); }
    else              { va = lerp4(r.a, r.b, wya); vb = lerp4(r.c, r.d, wyb); }
}

// Column-major sweep over the distinct feature columns of this pooled row.
// Each column is loaded exactly once; loads for column c+1 are issued before
// the vertical lerp of column c (distance-1 prefetch, branch-free vmem stream
// -> counted vmcnt waits). Outputs buffered in LDS; no global stores in-loop.
template <int RC>
__device__ __forceinline__ void run_row(const float* __restrict__ pbase,
                                        float4* __restrict__ lbase,  // LDS, stride 128 per slot
                                        float nx1, float dx,
                                        int ro0, int ro1, int ro2, int ro3,
                                        float wya, float wyb)
{
    const float inv    = 1.0f / (float)(SAMPD - 1);
    const float wscale = (float)(WF - 1);

    // Per-sample effective processing column pc and x-weight w.
    // Sample sx is consumed when the sweep reaches column pc; value =
    // lerp(va[pc-1], va[pc], w). Identical arithmetic at every call site.
    auto samp = [&](int sx, int& pc, float& w) {
        float tx = (float)sx * inv;
        float xs = fmaf(dx, tx, nx1) * wscale;
        xs = fminf(fmaxf(xs, 0.0f), wscale);
        float x0f = floorf(xs);
        int ci = (int)x0f;
        float wx = xs - x0f;
        if (ci >= WF - 1) { pc = WF - 1; w = 1.0f; }  // right-edge clamp: pick va[WF-1]
        else              { pc = ci + 1; w = wx; }
        pc = __builtin_amdgcn_readfirstlane(pc);       // block-uniform -> scalar branch
    };

    int pc0, pcl; float w0, wl;
    samp(0, pc0, w0);
    samp(SAMPD - 1, pcl, wl);
    int cfirst = pc0 - 1;   // pc is monotone nondecreasing; pc(0) == cfirst+1
    int clast  = pcl;       // pc(13) == clast, so every sample is consumed

    // Prologue: column cfirst -> vaP/vbP, issue loads for cfirst+1.
    Raw r0 = loadraw<RC>(pbase, cfirst, ro0, ro1, ro2, ro3);
    Raw rA = loadraw<RC>(pbase, cfirst + 1, ro0, ro1, ro2, ro3);
    Raw rB;
    float4 vaP, vbP;
    vlerp<RC>(r0, wya, wyb, vaP, vbP);

    float4 m0 = make_float4(-INFINITY, -INFINITY, -INFINITY, -INFINITY);
    int sx = 0;
    int c  = cfirst + 1;

    // Consume every sample whose processing column == c. No vmem except the
    // LDS stash, so outstanding-load counts stay consistent across the CFG.
    auto consume = [&](float4 vaC, float4 vbC) {
        for (;;) {
            if (sx >= SAMPD) break;
            int pc; float w;
            samp(sx, pc, w);
            if (pc > c) break;
            float4 sa = lerp4(vaP, vaC, w);
            float4 sb = lerp4(vbP, vbC, w);
            m0 = max4(m0, max4(sa, sb));
            if (sx & 1) {
                lbase[(sx >> 1) * 128] = m0;   // LDS stash (ds_write_b128)
                m0 = make_float4(-INFINITY, -INFINITY, -INFINITY, -INFINITY);
            }
            ++sx;
        }
        vaP = vaC; vbP = vbC;
    };

    // Ping-pong main loop: consume one buffer while the other is in flight.
    for (;;) {
        {   // consume rA, prefetch into rB
            int cn = min(c + 1, clast);
            rB = loadraw<RC>(pbase, cn, ro0, ro1, ro2, ro3);
            float4 vaC, vbC;
            vlerp<RC>(rA, wya, wyb, vaC, vbC);
            consume(vaC, vbC);
            if (c == clast) return;
            ++c;
        }
        {   // consume rB, prefetch into rA
            int cn = min(c + 1, clast);
            rA = loadraw<RC>(pbase, cn, ro0, ro1, ro2, ro3);
            float4 vaC, vbC;
            vlerp<RC>(rB, wya, wyb, vaC, vbC);
            consume(vaC, vbC);
            if (c == clast) return;
            ++c;
        }
    }
}

// One block per (roi, pooled_row). 128 threads * float4 = 512 channels.
__global__ __launch_bounds__(128, 4) void roipool_kernel(
    const float* __restrict__ feat,    // [HF, WF, CC]
    const float* __restrict__ rois,    // [N, 4] (x1,y1,x2,y2)
    const int*   __restrict__ im_size, // [2] (h, w)
    float*       __restrict__ out,     // [N, 7, 7, CC]
    int N)
{
    __shared__ float4 lds_out[POOLD * 128];   // 14336 B

    int bid = blockIdx.x;
    int n   = bid / POOLD;
    int py  = bid - n * POOLD;
    if (n >= N) return;

    float h = (float)im_size[0];
    float w = (float)im_size[1];
    float4 box = *(const float4*)(rois + 4 * n);
    float ny1 = box.y / h, nx1 = box.x / w;
    float ny2 = box.w / h, nx2 = box.z / w;
    float dx = nx2 - nx1;

    const float inv = 1.0f / (float)(SAMPD - 1);

    // vertical taps for the two sample rows of this pooled row (block-uniform)
    float tya = (float)(2 * py) * inv;
    float tyb = (float)(2 * py + 1) * inv;
    float ysa = (ny1 + (ny2 - ny1) * tya) * (float)(HF - 1);
    float ysb = (ny1 + (ny2 - ny1) * tyb) * (float)(HF - 1);
    ysa = fminf(fmaxf(ysa, 0.0f), (float)(HF - 1));
    ysb = fminf(fmaxf(ysb, 0.0f), (float)(HF - 1));
    float y0fa = floorf(ysa);
    float y0fb = floorf(ysb);
    float wya = ysa - y0fa;
    float wyb = ysb - y0fb;
    int iya = __builtin_amdgcn_readfirstlane((int)y0fa);
    int iyb = __builtin_amdgcn_readfirstlane((int)y0fb);
    int iya1 = min(iya + 1, HF - 1);
    int iyb1 = min(iyb + 1, HF - 1);
    int ro0 = iya  * (WF * CC);
    int ro1 = iya1 * (WF * CC);
    int ro2 = iyb  * (WF * CC);
    int ro3 = iyb1 * (WF * CC);

    const float* pbase = feat + (size_t)threadIdx.x * 4;
    float4* lbase = lds_out + threadIdx.x;
    float* obase = out + ((size_t)(n * POOLD + py) * POOLD) * CC + (size_t)threadIdx.x * 4;

    // Row-sharing case is fixed for the whole block -> one scalar dispatch.
    if (ro2 == ro0) {
        run_row<0>(pbase, lbase, nx1, dx, ro0, ro1, ro2, ro3, wya, wyb);
    } else if (ro2 == ro1) {
        run_row<1>(pbase, lbase, nx1, dx, ro0, ro1, ro2, ro3, wya, wyb);
    } else {
        run_row<2>(pbase, lbase, nx1, dx, ro0, ro1, ro2, ro3, wya, wyb);
    }

    // Epilogue: straight-line LDS -> global NT stores (fire-and-forget).
    #pragma unroll
    for (int p = 0; p < POOLD; ++p) {
        float4 v = lbase[p * 128];
        store_nt4(obase + (size_t)p * CC, v);
    }
}

extern "C" void kernel_launch(void* const* d_in, const int* in_sizes, int n_in,
                              void* d_out, int out_size, void* d_ws, size_t ws_size,
                              hipStream_t stream) {
    const float* feat    = (const float*)d_in[0];   // [1,37,50,512]
    const float* rois    = (const float*)d_in[1];   // [N,4]
    const int*   im_size = (const int*)d_in[2];     // [2]
    float* out = (float*)d_out;

    int N = in_sizes[1] / 4;
    int nblocks = N * POOLD;
    roipool_kernel<<<nblocks, 128, 0, stream>>>(feat, rois, im_size, out, N);
}